// Round 5
// baseline (88.462 us; speedup 1.0000x reference)
//
#include <hip/hip_runtime.h>
#include <stdint.h>

#define BATCH   2048
#define INDIM   512
#define OUTDIM  512
#define SDIM    8
#define KTOT    4096
#define PSTRIDE 68                 // f32 per plane row (bank-skewed: 68%32=4)
#define PSZ     (64 * PSTRIDE)     // 4352 f32 per plane

typedef __attribute__((ext_vector_type(4))) float  f32x4;
typedef __attribute__((ext_vector_type(8))) __bf16 bf16x8;
typedef __attribute__((ext_vector_type(8))) unsigned short u16x8;

__device__ __forceinline__ unsigned short f2bf(float x) {
  unsigned int u = __float_as_uint(x);
  u += 0x7fffu + ((u >> 16) & 1u);      // round-to-nearest-even
  return (unsigned short)(u >> 16);
}

__device__ __forceinline__ void llds16(const void* g, void* s) {
  __builtin_amdgcn_global_load_lds(
      (__attribute__((address_space(1))) void*)g,
      (__attribute__((address_space(3))) void*)s, 16, 0, 0);
}

__device__ __forceinline__ void mkbasis(float t, float* bs) {
  bs[0] = 1.0f; bs[1] = t; bs[2] = t * t; bs[3] = bs[2] * t;
  const float kn[4] = {0.2f, 0.4f, 0.6f, 0.8f};
#pragma unroll
  for (int c = 0; c < 4; ++c) {
    float d = fmaxf(t - kn[c], 0.0f);
    bs[4 + c] = d * d * d;
  }
}

// ---------------------------------------------------------------------------
// prep (unchanged from R4, proven):
//   blocks [  0, 512): Bt[n][k] = bf16(W[k*512+n])
//   blocks [512,1024): Fbf[b][i] = bf16(inp[b][1+i]); basis table (f32)
// ---------------------------------------------------------------------------
__global__ __launch_bounds__(256) void prep_kernel(
    const float* __restrict__ inp, const float* __restrict__ W,
    unsigned short* __restrict__ Fbf, unsigned short* __restrict__ Btf,
    float* __restrict__ Bas) {
  const int tid = threadIdx.x;
  const int bx  = blockIdx.x;
  if (bx < 512) {
    const int kt = bx >> 3, ntile = bx & 7;
    const int k0 = kt * 64, n0 = ntile * 64;
    __shared__ float Ts[64][65];           // [n_local][k_local], padded
#pragma unroll
    for (int p = 0; p < 4; ++p) {
      const int r  = (tid >> 4) + p * 16;  // k-local
      const int c4 = (tid & 15) * 4;       // n-local
      float4 v = *(const float4*)&W[(size_t)(k0 + r) * 512 + n0 + c4];
      Ts[c4 + 0][r] = v.x; Ts[c4 + 1][r] = v.y;
      Ts[c4 + 2][r] = v.z; Ts[c4 + 3][r] = v.w;
    }
    __syncthreads();
    const int nl  = tid >> 2;              // 0..63
    const int kcc = (tid & 3) * 16;        // 0,16,32,48
    u16x8 o0, o1;
#pragma unroll
    for (int q = 0; q < 8; ++q) {
      o0[q] = f2bf(Ts[nl][kcc + q]);
      o1[q] = f2bf(Ts[nl][kcc + 8 + q]);
    }
    unsigned short* dst = Btf + (size_t)(n0 + nl) * KTOT + k0 + kcc;
    *(u16x8*)dst = o0;
    *(u16x8*)(dst + 8) = o1;
  } else {
    const int b0   = (bx - 512) * 4;
    const int b    = b0 + (tid >> 6);
    const int i0   = (tid & 63) * 8;
    const float* row = inp + (size_t)b * (INDIM + 1);
    u16x8 o;
#pragma unroll
    for (int q = 0; q < 8; ++q) o[q] = f2bf(row[1 + i0 + q]);
    *(u16x8*)(Fbf + (size_t)b * INDIM + i0) = o;
    if (tid < 4) {
      const int bb = b0 + tid;
      float t = inp[(size_t)bb * (INDIM + 1)];
      float bs[8]; mkbasis(t, bs);
      f32x4 lo = {bs[0], bs[1], bs[2], bs[3]};
      f32x4 hi = {bs[4], bs[5], bs[6], bs[7]};
      *(f32x4*)(Bas + (size_t)bb * 8)     = lo;
      *(f32x4*)(Bas + (size_t)bb * 8 + 4) = hi;
    }
  }
}

// ---------------------------------------------------------------------------
// GEMM (R4 structure + explicit B register double-buffer):
// grid 256 (one 64x64 tile/block, 1/CU), 512 thr = 8 waves (2/SIMD).
// Wave w computes the FULL tile for slice s=w (K=512): A staged once in LDS
// (XOR-swizzled via pre-swizzled global source), B fragments direct-from-L2,
// NO barriers in the main loop. NEW: ks=0 B loads issued BEFORE the A-stage
// barrier (latency hides under the vmcnt drain); ks+1 fragments prefetched
// while MFMA-ing ks; loop fully unrolled so all regs are statically indexed.
// Epilogue: raw partials -> 8 bank-skewed LDS planes, then per-thread
// out = sum_w Bas[row][w]*(plane_w + b_wts[w]); pure stores, zero atomics.
// ---------------------------------------------------------------------------
__global__ __launch_bounds__(512, 2) void gemm_kernel(
    const unsigned short* __restrict__ Fbf,
    const unsigned short* __restrict__ Btf,
    const float* __restrict__ Bas,
    const float* __restrict__ bwts,
    float* __restrict__ out) {
  const int tid  = threadIdx.x;
  const int tile = blockIdx.x;           // 256 = 32 m-tiles x 8 n-tiles
  const int nt = tile & 7, mt = tile >> 3;
  const int m0 = mt * 64, n0 = nt * 64;
  const int w = tid >> 6;                // wave id == slice id, 0..7
  const int l = tid & 63;
  const int quad = l >> 4, lr = l & 15;

  __shared__ __align__(16) float smem[8 * PSZ];       // 139264 B
  unsigned short* Alds = (unsigned short*)smem;       // A region: [0, 64 KB)

  // ---- stage A (64 x 512 bf16) once: 8 llds16 per thread ----
#pragma unroll
  for (int j = 0; j < 8; ++j) {
    const int f   = j * 512 + tid;       // flat 16B-chunk index 0..4095
    const int row = f >> 6;              // 0..63
    const int cs  = (f & 63) ^ (row & 7);
    llds16(Fbf + (size_t)(m0 + row) * INDIM + cs * 8, &Alds[f * 8]);
  }

  // ---- B base pointers: row (n0 + j*16 + lr), slice w, quad's 8-elem chunk
  const unsigned short* bptr[4];
#pragma unroll
  for (int j = 0; j < 4; ++j)
    bptr[j] = Btf + (size_t)(n0 + j * 16 + lr) * KTOT + w * 512 + quad * 8;

  // prefetch ks=0 B fragments BEFORE the barrier: their ~L2 latency drains
  // together with the llds16 vmcnt wait inside __syncthreads.
  bf16x8 bcur[4], bnxt[4];
#pragma unroll
  for (int j = 0; j < 4; ++j)
    bcur[j] = *(const bf16x8*)(bptr[j]);

  __syncthreads();                       // drains llds; A ready for all waves

  const int sx = lr & 7;
  f32x4 acc[4][4] = {};

#pragma unroll
  for (int ks = 0; ks < 16; ++ks) {      // K = 512, 32 per step, no barriers
    if (ks < 15) {
#pragma unroll
      for (int j = 0; j < 4; ++j)
        bnxt[j] = *(const bf16x8*)(bptr[j] + (ks + 1) * 32);
    }
    bf16x8 afr[4];
    const int c = ((ks * 4 + quad) ^ sx) * 8;
#pragma unroll
    for (int i = 0; i < 4; ++i)
      afr[i] = *(const bf16x8*)&Alds[(i * 16 + lr) * 512 + c];
#pragma unroll
    for (int i = 0; i < 4; ++i)
#pragma unroll
      for (int j = 0; j < 4; ++j)
        acc[i][j] = __builtin_amdgcn_mfma_f32_16x16x32_bf16(afr[i], bcur[j], acc[i][j], 0, 0, 0);
#pragma unroll
    for (int j = 0; j < 4; ++j)
      bcur[j] = bnxt[j];                 // register rename, free
  }

  __syncthreads();                       // everyone done reading Alds

  // ---- dump raw partial to plane w (C/D: row = quad*4+reg, col = lr) ----
  float* P = smem + w * PSZ;
#pragma unroll
  for (int i = 0; i < 4; ++i)
#pragma unroll
    for (int j = 0; j < 4; ++j)
#pragma unroll
      for (int r = 0; r < 4; ++r)
        P[(i * 16 + quad * 4 + r) * PSTRIDE + j * 16 + lr] = acc[i][j][r];

  __syncthreads();

  // ---- reduce + bias + store: thread -> row tid>>3, cols (tid&7)*8 .. +8 ----
  const int row  = tid >> 3;
  const int col8 = (tid & 7) * 8;
  const float* brow = Bas + (size_t)(m0 + row) * 8;
  f32x4 s0 = {}, s1 = {};
#pragma unroll
  for (int ww = 0; ww < 8; ++ww) {
    const float bw = brow[ww];
    const float* Pr = smem + ww * PSZ + row * PSTRIDE + col8;
    const float* Wr = bwts + (size_t)ww * OUTDIM + n0 + col8;
    f32x4 v0 = *(const f32x4*)Pr + *(const f32x4*)Wr;
    f32x4 v1 = *(const f32x4*)(Pr + 4) + *(const f32x4*)(Wr + 4);
    s0 += v0 * bw;
    s1 += v1 * bw;
  }
  float* op = out + (size_t)(m0 + row) * OUTDIM + n0 + col8;
  *(f32x4*)op       = s0;
  *(f32x4*)(op + 4) = s1;
}

extern "C" void kernel_launch(void* const* d_in, const int* in_sizes, int n_in,
                              void* d_out, int out_size, void* d_ws, size_t ws_size,
                              hipStream_t stream) {
  const float* inp  = (const float*)d_in[0];   // (2048, 513)
  const float* W    = (const float*)d_in[1];   // (8, 262144) == (4096, 512) row-major
  const float* bwts = (const float*)d_in[2];   // (8, 512)
  float* out = (float*)d_out;

  unsigned short* Fbf = (unsigned short*)d_ws;                  // 2 MB
  unsigned short* Btf = Fbf + (size_t)BATCH * INDIM;            // 4 MB
  float*          Bas = (float*)(Btf + (size_t)OUTDIM * KTOT);  // 64 KB

  prep_kernel<<<1024, 256, 0, stream>>>(inp, W, Fbf, Btf, Bas);
  gemm_kernel<<<(BATCH / 64) * (OUTDIM / 64), 512, 0, stream>>>(Fbf, Btf, Bas, bwts, out);
}